// Round 15
// baseline (2881.274 us; speedup 1.0000x reference)
//
#include <hip/hip_runtime.h>
#include <hip/hip_bf16.h>
#include <math.h>

#define T_STEPS 512
#define BATCH   64
#define IN_DIM  1024
#define HID     1024
#define BH_SZ   (BATCH * HID)

typedef short bf16x8 __attribute__((ext_vector_type(8)));
typedef float f32x4  __attribute__((ext_vector_type(4)));
typedef unsigned u32x4 __attribute__((ext_vector_type(4)));
typedef unsigned long long u64;

// ---- coherent (agent-scope, cache-bypassing) accessors --------------------
__device__ __forceinline__ unsigned ld_coh_u32(const unsigned* p) {
    return __hip_atomic_load(p, __ATOMIC_RELAXED, __HIP_MEMORY_SCOPE_AGENT);
}
__device__ __forceinline__ void st_coh_u32(unsigned* p, unsigned v) {
    __hip_atomic_store(p, v, __ATOMIC_RELAXED, __HIP_MEMORY_SCOPE_AGENT);
}
__device__ __forceinline__ u64 ld_coh_u64(const u64* p) {
    return __hip_atomic_load(p, __ATOMIC_RELAXED, __HIP_MEMORY_SCOPE_AGENT);
}
__device__ __forceinline__ void st_coh_u64(u64* p, u64 v) {
    __hip_atomic_store(p, v, __ATOMIC_RELAXED, __HIP_MEMORY_SCOPE_AGENT);
}

// ---- bf16 split helpers (RNE) ---------------------------------------------
__device__ __forceinline__ unsigned short f2bf(float x) {
    unsigned u = __builtin_bit_cast(unsigned, x);
    unsigned r = u + 0x7FFFu + ((u >> 16) & 1u);
    return (unsigned short)(r >> 16);
}
__device__ __forceinline__ float bf2f(unsigned short h) {
    unsigned u = ((unsigned)h) << 16;
    return __builtin_bit_cast(float, u);
}
__device__ __forceinline__ float fast_tanh(float x) {
    float e = __expf(2.0f * x);
    return 1.0f - 2.0f * __builtin_amdgcn_rcpf(e + 1.0f);
}
__device__ __forceinline__ unsigned pack_hl(float v) {
    unsigned short hi = f2bf(v);
    unsigned short lo = f2bf(v - bf2f(hi));
    return (unsigned)hi | ((unsigned)lo << 16);
}

// ---------------------------------------------------------------------------
// one-time x pre-pack: f32 -> bf16 (RNE, hi only), vectorized 8-wide
// ---------------------------------------------------------------------------
__global__ __launch_bounds__(256) void pack_x_kernel(
    const float* __restrict__ src, unsigned short* __restrict__ dst, int n8)
{
    int idx = blockIdx.x * 256 + threadIdx.x;
    int stride = gridDim.x * 256;
    for (int i = idx; i < n8; i += stride) {
        float4 a = *(const float4*)(src + (size_t)i * 8);
        float4 b = *(const float4*)(src + (size_t)i * 8 + 4);
        float vv[8] = {a.x, a.y, a.z, a.w, b.x, b.y, b.z, b.w};
        bf16x8 o;
        #pragma unroll
        for (int e = 0; e < 8; e++) o[e] = (short)f2bf(vv[e]);
        *(bf16x8*)(dst + (size_t)i * 8) = o;
    }
}

// ---------------------------------------------------------------------------
// Fused RNN kernel v15 = v14 with the producer path single-waved:
//  - wave 0 owns ALL 256 outputs (4/lane): reduce -> tanh -> 2x packed-u64
//    coherent stores -> in-wave s_waitcnt vmcnt(0) -> lane0 flag store.
//    vmcnt is wave-level, so the waitcnt gives the SAME flag-after-all-h-
//    stores ordering sync C provided (a barrier drain is built from this
//    very mechanism) -> sync C deleted (3 barriers/step).
//  - waves 1-7 start Xh staging right after sync B (448-thread guarded loop).
//  - wave 0 polls AFTER its store/out work (v13 bubble-then-poll timing,
//    s_sleep(4) throttle). Full-grid 256-flag poll: FROZEN INVARIANT.
//  - arithmetic bit-identical to v14 (same Pred order, bias, tanh).
// LDS: Wih 32K + Hhi 32K + Hlo 32K + Xh 32K + Pred 8K = 136 KB.
// ---------------------------------------------------------------------------
__global__ __launch_bounds__(512, 1) void rnn_fused_kernel(
    const float* __restrict__ x,      // [T][B][I] raw input (fallback)
    const unsigned short* __restrict__ xp16,  // packed bf16 x or nullptr
    const float* __restrict__ h0,     // [B][H]
    const float* __restrict__ W_ih,   // [H][I]
    const float* __restrict__ Whh,    // [H][H]
    const float* __restrict__ b_ih,   // [H]
    const float* __restrict__ b_hh,   // [H]
    float* __restrict__ out,          // [T][B][H] h out; h_last at end
    unsigned* hcomm,                  // [2][B][H] packed bf16 hi/lo exchange
    unsigned* flags)                  // [256*32] zeroed
{
    __shared__ unsigned short Wih[16 * 1024];   // W_ih rows j0.., bf16 hi only
    __shared__ unsigned short Hhi[16 * 1024];
    __shared__ unsigned short Hlo[16 * 1024];
    __shared__ unsigned short Xh [16 * 1024];   // x_t rows b0.., bf16
    __shared__ f32x4 Pred[8][64];

    const int bid = blockIdx.x;
    const int j0 = (bid & 63) * 16;
    const int b0 = (bid >> 6) * 16;
    const int tid  = threadIdx.x;
    const int lane = tid & 63;
    const int w    = tid >> 6;        // wave 0..7 -> k-range [w*128,(w+1)*128)

    // fragment addressing
    const int frow = lane & 15;
    const int ksub = (lane >> 4) * 8;          // 0,8,16,24
    const int sw   = (frow & 7) << 3;

    // ---- prologue 1: stage W_ih rows j0..j0+15 (bf16 hi), XOR-swizzled ----
    #pragma unroll
    for (int i = 0; i < 4; i++) {
        int c = i * 512 + tid;
        int row = c >> 7;
        int k0 = (c & 127) * 8;
        const float* src = W_ih + (size_t)(j0 + row) * IN_DIM + k0;
        float4 v0 = *(const float4*)(src);
        float4 v1 = *(const float4*)(src + 4);
        float vv[8] = {v0.x, v0.y, v0.z, v0.w, v1.x, v1.y, v1.z, v1.w};
        bf16x8 hi8;
        #pragma unroll
        for (int e = 0; e < 8; e++) hi8[e] = (short)f2bf(vv[e]);
        int ofs = row * 1024 + (k0 ^ ((row & 7) << 3));
        *(bf16x8*)&Wih[ofs] = hi8;
    }

    // ---- prologue 2: stage W_hh split into Hhi/Hlo (TEMP), read frags ----
    #pragma unroll
    for (int i = 0; i < 4; i++) {
        int c = i * 512 + tid;
        int row = c >> 7;
        int k0 = (c & 127) * 8;
        const float* src = Whh + (size_t)(j0 + row) * HID + k0;
        float4 v0 = *(const float4*)(src);
        float4 v1 = *(const float4*)(src + 4);
        float vv[8] = {v0.x, v0.y, v0.z, v0.w, v1.x, v1.y, v1.z, v1.w};
        bf16x8 hi8, lo8;
        #pragma unroll
        for (int e = 0; e < 8; e++) {
            unsigned short h = f2bf(vv[e]);
            hi8[e] = (short)h;
            lo8[e] = (short)f2bf(vv[e] - bf2f(h));
        }
        int ofs = row * 1024 + (k0 ^ ((row & 7) << 3));
        *(bf16x8*)&Hhi[ofs] = hi8;
        *(bf16x8*)&Hlo[ofs] = lo8;
    }
    __syncthreads();
    bf16x8 wh[4], wl[4];                       // W_hh frags in registers
    #pragma unroll
    for (int kk = 0; kk < 4; kk++) {
        int kidx = w * 128 + kk * 32 + ksub;
        int ofs  = frow * 1024 + (kidx ^ sw);
        wh[kk] = *(const bf16x8*)&Hhi[ofs];
        wl[kk] = *(const bf16x8*)&Hlo[ofs];
    }
    __syncthreads();   // frags read -> Hhi/Hlo reusable for h staging

    // ---- prologue 3: stage x_0 into Xh (all 512 threads) ----
    if (xp16) {
        #pragma unroll
        for (int i = 0; i < 4; i++) {
            int c = i * 512 + tid;
            int row = c >> 7;
            int k0 = (c & 127) * 8;
            bf16x8 hi8 = *(const bf16x8*)(xp16 + (size_t)(b0 + row) * IN_DIM + k0);
            int ofs = row * 1024 + (k0 ^ ((row & 7) << 3));
            *(bf16x8*)&Xh[ofs] = hi8;
        }
    } else {
        #pragma unroll
        for (int i = 0; i < 4; i++) {
            int c = i * 512 + tid;
            int row = c >> 7;
            int k0 = (c & 127) * 8;
            const float* p = x + (size_t)(b0 + row) * IN_DIM + k0;
            float4 v0 = *(const float4*)(p);
            float4 v1 = *(const float4*)(p + 4);
            float vv[8] = {v0.x, v0.y, v0.z, v0.w, v1.x, v1.y, v1.z, v1.w};
            bf16x8 hi8;
            #pragma unroll
            for (int e = 0; e < 8; e++) hi8[e] = (short)f2bf(vv[e]);
            int ofs = row * 1024 + (k0 ^ ((row & 7) << 3));
            *(bf16x8*)&Xh[ofs] = hi8;
        }
    }

    // ---- wave-0 output mapping: lane l owns outputs o = 4l..4l+3 ----
    // o: b = o>>4, j = o&15; Pred[k][plane][pr], plane = ((b>>2)<<4)|j,
    // pr = b&3. For o = 4l+i: b = l>>2 (const per lane), j = (4l&15)+i.
    const int bloc  = lane >> 2;               // 0..15
    const int jb    = (4 * lane) & 15;         // 0,4,8,12
    const int prr   = bloc & 3;
    const int pbase = (bloc >> 2) << 4;
    const size_t woff = (size_t)(b0 + bloc) * HID + j0 + jb;  // 16B aligned
    float bias4[4];
    if (tid < 64) {
        #pragma unroll
        for (int i = 0; i < 4; i++)
            bias4[i] = b_ih[j0 + jb + i] + b_hh[j0 + jb + i];
    }

    for (int t = 0; t < T_STEPS; t++) {
        // ---- stage h_{t-1} (16 rows) into Hhi/Hlo (all 512 threads) ----
        if (t == 0) {
            #pragma unroll
            for (int i = 0; i < 4; i++) {
                int c = i * 512 + tid;
                int row = c >> 7;
                int k0 = (c & 127) * 8;
                const float* p = h0 + (size_t)(b0 + row) * HID + k0;
                float4 v0 = *(const float4*)(p);
                float4 v1 = *(const float4*)(p + 4);
                float vv[8] = {v0.x, v0.y, v0.z, v0.w, v1.x, v1.y, v1.z, v1.w};
                bf16x8 hi8, lo8;
                #pragma unroll
                for (int e = 0; e < 8; e++) {
                    unsigned short h = f2bf(vv[e]);
                    hi8[e] = (short)h;
                    lo8[e] = (short)f2bf(vv[e] - bf2f(h));
                }
                int ofs = row * 1024 + (k0 ^ ((row & 7) << 3));
                *(bf16x8*)&Hhi[ofs] = hi8;
                *(bf16x8*)&Hlo[ofs] = lo8;
            }
        } else {
            const u64* hsrc64 = (const u64*)(hcomm + (size_t)((t + 1) & 1) * BH_SZ);
            u64 pv[16];
            #pragma unroll
            for (int i = 0; i < 4; i++) {
                int c = i * 512 + tid;
                int row = c >> 7;
                int k0 = (c & 127) * 8;
                const u64* p = hsrc64 + (((size_t)(b0 + row) * HID + k0) >> 1);
                #pragma unroll
                for (int e = 0; e < 4; e++)
                    pv[i * 4 + e] = ld_coh_u64(p + e);
            }
            #pragma unroll
            for (int i = 0; i < 4; i++) {
                int c = i * 512 + tid;
                int row = c >> 7;
                int k0 = (c & 127) * 8;
                u32x4 hiu, lou;
                #pragma unroll
                for (int e = 0; e < 4; e++) {
                    u64 q = pv[i * 4 + e];
                    unsigned p0 = (unsigned)q;
                    unsigned p1 = (unsigned)(q >> 32);
                    hiu[e] = (p0 & 0xFFFFu) | (p1 << 16);
                    lou[e] = (p0 >> 16) | (p1 & 0xFFFF0000u);
                }
                int ofs = row * 1024 + (k0 ^ ((row & 7) << 3));
                *(u32x4*)&Hhi[ofs] = hiu;
                *(u32x4*)&Hlo[ofs] = lou;
            }
        }
        __syncthreads();   // sync A

        // ---- MFMA: W_hh·h (3-term, reg frags) + W_ih·x_t (1-term) ----
        {
            f32x4 acc0 = {0.f, 0.f, 0.f, 0.f};
            f32x4 acc1 = {0.f, 0.f, 0.f, 0.f};
            #pragma unroll
            for (int kk = 0; kk < 4; kk++) {
                int kidx = w * 128 + kk * 32 + ksub;
                int ofs  = frow * 1024 + (kidx ^ sw);
                bf16x8 ahi = *(const bf16x8*)&Hhi[ofs];
                bf16x8 alo = *(const bf16x8*)&Hlo[ofs];
                bf16x8 xh  = *(const bf16x8*)&Xh[ofs];
                bf16x8 wi  = *(const bf16x8*)&Wih[ofs];
                acc0 = __builtin_amdgcn_mfma_f32_16x16x32_bf16(ahi, wh[kk], acc0, 0, 0, 0);
                acc1 = __builtin_amdgcn_mfma_f32_16x16x32_bf16(ahi, wl[kk], acc1, 0, 0, 0);
                acc0 = __builtin_amdgcn_mfma_f32_16x16x32_bf16(alo, wh[kk], acc0, 0, 0, 0);
                acc1 = __builtin_amdgcn_mfma_f32_16x16x32_bf16(xh,  wi,     acc1, 0, 0, 0);
            }
            Pred[w][lane] = acc0 + acc1;
        }
        __syncthreads();   // sync B

        if (tid < 64) {
            // ---- wave 0: reduce 4 outputs, tanh, coherent h stores,
            //      in-wave drain, flag, out stores, throttled poll ----
            float hn4[4];
            #pragma unroll
            for (int i = 0; i < 4; i++) {
                float s = bias4[i];
                const int plane = pbase | (jb + i);
                #pragma unroll
                for (int k = 0; k < 8; k++) s += Pred[k][plane][prr];
                hn4[i] = fast_tanh(s);
            }
            u64* dst = (u64*)(hcomm + (size_t)(t & 1) * BH_SZ + woff);
            u64 w0 = (u64)pack_hl(hn4[0]) | ((u64)pack_hl(hn4[1]) << 32);
            u64 w1 = (u64)pack_hl(hn4[2]) | ((u64)pack_hl(hn4[3]) << 32);
            st_coh_u64(dst, w0);
            st_coh_u64(dst + 1, w1);
            asm volatile("s_waitcnt vmcnt(0)" ::: "memory");   // wave drain
            if (lane == 0) st_coh_u32(&flags[bid * 32], (unsigned)(t + 1));
            float4 o4 = make_float4(hn4[0], hn4[1], hn4[2], hn4[3]);
            *(float4*)(out + (size_t)t * BH_SZ + woff) = o4;
            if (t == T_STEPS - 1)
                *(float4*)(out + (size_t)T_STEPS * BH_SZ + woff) = o4;
            // poll: full grid, s_sleep(4) backoff (frozen invariant)
            const unsigned target = (unsigned)(t + 1);
            for (;;) {
                int ok = 1;
                #pragma unroll
                for (int g = 0; g < 4; g++) {
                    unsigned v = ld_coh_u32(&flags[(size_t)(lane + g * 64) * 32]);
                    ok &= (v >= target) ? 1 : 0;
                }
                if (__all(ok)) break;
                __builtin_amdgcn_s_sleep(4);
            }
        } else if (t + 1 < T_STEPS) {
            // ---- waves 1-7: stage x_{t+1} into Xh (reads done at sync B) ----
            const int tt = tid - 64;           // 0..447
            if (xp16) {
                const unsigned short* xs = xp16 + (size_t)(t + 1) * BH_SZ;
                #pragma unroll
                for (int i = 0; i < 5; i++) {
                    int c = i * 448 + tt;
                    if (c < 2048) {
                        int row = c >> 7;
                        int k0 = (c & 127) * 8;
                        bf16x8 hi8 = *(const bf16x8*)(xs + (size_t)(b0 + row) * IN_DIM + k0);
                        int ofs = row * 1024 + (k0 ^ ((row & 7) << 3));
                        *(bf16x8*)&Xh[ofs] = hi8;
                    }
                }
            } else {
                const float* xs = x + (size_t)(t + 1) * BH_SZ;
                #pragma unroll
                for (int i = 0; i < 5; i++) {
                    int c = i * 448 + tt;
                    if (c < 2048) {
                        int row = c >> 7;
                        int k0 = (c & 127) * 8;
                        const float* p = xs + (size_t)(b0 + row) * IN_DIM + k0;
                        float4 v0 = *(const float4*)(p);
                        float4 v1 = *(const float4*)(p + 4);
                        float vv[8] = {v0.x, v0.y, v0.z, v0.w,
                                       v1.x, v1.y, v1.z, v1.w};
                        bf16x8 hi8;
                        #pragma unroll
                        for (int e = 0; e < 8; e++) hi8[e] = (short)f2bf(vv[e]);
                        int ofs = row * 1024 + (k0 ^ ((row & 7) << 3));
                        *(bf16x8*)&Xh[ofs] = hi8;
                    }
                }
            }
        }

        __syncthreads();   // sync D: poll done + Xh staged, step boundary
    }
}

// ---------------------------------------------------------------------------
extern "C" void kernel_launch(void* const* d_in, const int* in_sizes, int n_in,
                              void* d_out, int out_size, void* d_ws, size_t ws_size,
                              hipStream_t stream)
{
    const float* input  = (const float*)d_in[0];  // [T,B,I]
    const float* hidden = (const float*)d_in[1];  // [B,H]
    const float* W_ih   = (const float*)d_in[2];  // [H,I]
    const float* W_hh   = (const float*)d_in[3];  // [H,H]
    const float* b_ih   = (const float*)d_in[4];  // [H]
    const float* b_hh   = (const float*)d_in[5];  // [H]
    float* out = (float*)d_out;

    unsigned* flags = (unsigned*)d_ws;                          // 32 KB
    unsigned* hcomm = (unsigned*)((char*)d_ws + 256 * 32 * sizeof(unsigned));
    hipMemsetAsync(flags, 0, 256 * 32 * sizeof(unsigned), stream);

    // optional pre-packed x (bf16) at ws offset 1 MB, if workspace allows
    const size_t xpk_off  = (size_t)1 << 20;
    const size_t xpk_size = (size_t)T_STEPS * BH_SZ * sizeof(unsigned short);
    const unsigned short* xp16 = nullptr;
    if (ws_size >= xpk_off + xpk_size) {
        unsigned short* xp = (unsigned short*)((char*)d_ws + xpk_off);
        pack_x_kernel<<<2048, 256, 0, stream>>>(input, xp,
                                                (T_STEPS * BATCH * IN_DIM) / 8);
        xp16 = xp;
    }

    rnn_fused_kernel<<<256, 512, 0, stream>>>(
        input, xp16, hidden, W_ih, W_hh, b_ih, b_hh, out, hcomm, flags);
}

// Round 16
// 2310.001 us; speedup vs baseline: 1.2473x; 1.2473x over previous
//
#include <hip/hip_runtime.h>
#include <hip/hip_bf16.h>
#include <math.h>

#define T_STEPS 512
#define BATCH   64
#define IN_DIM  1024
#define HID     1024
#define BH_SZ   (BATCH * HID)

typedef short bf16x8 __attribute__((ext_vector_type(8)));
typedef float f32x4  __attribute__((ext_vector_type(4)));
typedef unsigned u32x4 __attribute__((ext_vector_type(4)));
typedef unsigned long long u64;

// ---- coherent (agent-scope, cache-bypassing) accessors --------------------
__device__ __forceinline__ unsigned ld_coh_u32(const unsigned* p) {
    return __hip_atomic_load(p, __ATOMIC_RELAXED, __HIP_MEMORY_SCOPE_AGENT);
}
__device__ __forceinline__ void st_coh_u32(unsigned* p, unsigned v) {
    __hip_atomic_store(p, v, __ATOMIC_RELAXED, __HIP_MEMORY_SCOPE_AGENT);
}
__device__ __forceinline__ u64 ld_coh_u64(const u64* p) {
    return __hip_atomic_load(p, __ATOMIC_RELAXED, __HIP_MEMORY_SCOPE_AGENT);
}

// ---- bf16 split helpers (RNE) ---------------------------------------------
__device__ __forceinline__ unsigned short f2bf(float x) {
    unsigned u = __builtin_bit_cast(unsigned, x);
    unsigned r = u + 0x7FFFu + ((u >> 16) & 1u);
    return (unsigned short)(r >> 16);
}
__device__ __forceinline__ float bf2f(unsigned short h) {
    unsigned u = ((unsigned)h) << 16;
    return __builtin_bit_cast(float, u);
}
__device__ __forceinline__ float fast_tanh(float x) {
    float e = __expf(2.0f * x);
    return 1.0f - 2.0f * __builtin_amdgcn_rcpf(e + 1.0f);
}

// ---------------------------------------------------------------------------
// one-time x pre-pack: f32 -> bf16 (RNE, hi only), vectorized 8-wide
// ---------------------------------------------------------------------------
__global__ __launch_bounds__(256) void pack_x_kernel(
    const float* __restrict__ src, unsigned short* __restrict__ dst, int n8)
{
    int idx = blockIdx.x * 256 + threadIdx.x;
    int stride = gridDim.x * 256;
    for (int i = idx; i < n8; i += stride) {
        float4 a = *(const float4*)(src + (size_t)i * 8);
        float4 b = *(const float4*)(src + (size_t)i * 8 + 4);
        float vv[8] = {a.x, a.y, a.z, a.w, b.x, b.y, b.z, b.w};
        bf16x8 o;
        #pragma unroll
        for (int e = 0; e < 8; e++) o[e] = (short)f2bf(vv[e]);
        *(bf16x8*)(dst + (size_t)i * 8) = o;
    }
}

// ---------------------------------------------------------------------------
// Fused RNN kernel v16 == v14 VERBATIM (best measured: 2313 us total).
// v15's single-waved producer regressed (serialized epilogue, Pred-gather
// bank conflicts, broken out-store write-combining) -> reverted.
// Skeleton: 4 barriers/step, full-grid 256-flag poll [FROZEN INVARIANT
// after v5/v11 replay races], bubble-then-throttled-poll (s_sleep(4)),
// two-chain MFMA acc, pre-packed bf16 x.
// LDS: Wih 32K + Hhi 32K + Hlo 32K + Xh 32K + Pred 8K = 136 KB.
// ---------------------------------------------------------------------------
__global__ __launch_bounds__(512, 1) void rnn_fused_kernel(
    const float* __restrict__ x,      // [T][B][I] raw input (fallback)
    const unsigned short* __restrict__ xp16,  // packed bf16 x or nullptr
    const float* __restrict__ h0,     // [B][H]
    const float* __restrict__ W_ih,   // [H][I]
    const float* __restrict__ Whh,    // [H][H]
    const float* __restrict__ b_ih,   // [H]
    const float* __restrict__ b_hh,   // [H]
    float* __restrict__ out,          // [T][B][H] h out; h_last at end
    unsigned* hcomm,                  // [2][B][H] packed bf16 hi/lo exchange
    unsigned* flags)                  // [256*32] zeroed
{
    __shared__ unsigned short Wih[16 * 1024];   // W_ih rows j0.., bf16 hi only
    __shared__ unsigned short Hhi[16 * 1024];
    __shared__ unsigned short Hlo[16 * 1024];
    __shared__ unsigned short Xh [16 * 1024];   // x_t rows b0.., bf16
    __shared__ f32x4 Pred[8][64];

    const int bid = blockIdx.x;
    const int j0 = (bid & 63) * 16;
    const int b0 = (bid >> 6) * 16;
    const int tid  = threadIdx.x;
    const int lane = tid & 63;
    const int w    = tid >> 6;        // wave 0..7 -> k-range [w*128,(w+1)*128)

    // fragment addressing
    const int frow = lane & 15;
    const int ksub = (lane >> 4) * 8;          // 0,8,16,24
    const int sw   = (frow & 7) << 3;

    // ---- prologue 1: stage W_ih rows j0..j0+15 (bf16 hi), XOR-swizzled ----
    #pragma unroll
    for (int i = 0; i < 4; i++) {
        int c = i * 512 + tid;
        int row = c >> 7;
        int k0 = (c & 127) * 8;
        const float* src = W_ih + (size_t)(j0 + row) * IN_DIM + k0;
        float4 v0 = *(const float4*)(src);
        float4 v1 = *(const float4*)(src + 4);
        float vv[8] = {v0.x, v0.y, v0.z, v0.w, v1.x, v1.y, v1.z, v1.w};
        bf16x8 hi8;
        #pragma unroll
        for (int e = 0; e < 8; e++) hi8[e] = (short)f2bf(vv[e]);
        int ofs = row * 1024 + (k0 ^ ((row & 7) << 3));
        *(bf16x8*)&Wih[ofs] = hi8;
    }

    // ---- prologue 2: stage W_hh split into Hhi/Hlo (TEMP), read frags ----
    #pragma unroll
    for (int i = 0; i < 4; i++) {
        int c = i * 512 + tid;
        int row = c >> 7;
        int k0 = (c & 127) * 8;
        const float* src = Whh + (size_t)(j0 + row) * HID + k0;
        float4 v0 = *(const float4*)(src);
        float4 v1 = *(const float4*)(src + 4);
        float vv[8] = {v0.x, v0.y, v0.z, v0.w, v1.x, v1.y, v1.z, v1.w};
        bf16x8 hi8, lo8;
        #pragma unroll
        for (int e = 0; e < 8; e++) {
            unsigned short h = f2bf(vv[e]);
            hi8[e] = (short)h;
            lo8[e] = (short)f2bf(vv[e] - bf2f(h));
        }
        int ofs = row * 1024 + (k0 ^ ((row & 7) << 3));
        *(bf16x8*)&Hhi[ofs] = hi8;
        *(bf16x8*)&Hlo[ofs] = lo8;
    }
    __syncthreads();
    bf16x8 wh[4], wl[4];                       // W_hh frags in registers
    #pragma unroll
    for (int kk = 0; kk < 4; kk++) {
        int kidx = w * 128 + kk * 32 + ksub;
        int ofs  = frow * 1024 + (kidx ^ sw);
        wh[kk] = *(const bf16x8*)&Hhi[ofs];
        wl[kk] = *(const bf16x8*)&Hlo[ofs];
    }
    __syncthreads();   // frags read -> Hhi/Hlo reusable for h staging

    // ---- prologue 3: stage x_0 into Xh ----
    if (xp16) {
        #pragma unroll
        for (int i = 0; i < 4; i++) {
            int c = i * 512 + tid;
            int row = c >> 7;
            int k0 = (c & 127) * 8;
            bf16x8 hi8 = *(const bf16x8*)(xp16 + (size_t)(b0 + row) * IN_DIM + k0);
            int ofs = row * 1024 + (k0 ^ ((row & 7) << 3));
            *(bf16x8*)&Xh[ofs] = hi8;
        }
    } else {
        #pragma unroll
        for (int i = 0; i < 4; i++) {
            int c = i * 512 + tid;
            int row = c >> 7;
            int k0 = (c & 127) * 8;
            const float* p = x + (size_t)(b0 + row) * IN_DIM + k0;
            float4 v0 = *(const float4*)(p);
            float4 v1 = *(const float4*)(p + 4);
            float vv[8] = {v0.x, v0.y, v0.z, v0.w, v1.x, v1.y, v1.z, v1.w};
            bf16x8 hi8;
            #pragma unroll
            for (int e = 0; e < 8; e++) hi8[e] = (short)f2bf(vv[e]);
            int ofs = row * 1024 + (k0 ^ ((row & 7) << 3));
            *(bf16x8*)&Xh[ofs] = hi8;
        }
    }

    const int o = tid;                 // tid<256: b = o>>4, j = o&15
    const size_t out_off = (size_t)(b0 + (o >> 4)) * HID + (size_t)(j0 + (o & 15));
    float bias = 0.f;
    if (tid < 256) bias = b_ih[j0 + (o & 15)] + b_hh[j0 + (o & 15)];

    for (int t = 0; t < T_STEPS; t++) {
        // ---- stage h_{t-1} (16 rows) into Hhi/Hlo (v7 verbatim) ----
        if (t == 0) {
            #pragma unroll
            for (int i = 0; i < 4; i++) {
                int c = i * 512 + tid;
                int row = c >> 7;
                int k0 = (c & 127) * 8;
                const float* p = h0 + (size_t)(b0 + row) * HID + k0;
                float4 v0 = *(const float4*)(p);
                float4 v1 = *(const float4*)(p + 4);
                float vv[8] = {v0.x, v0.y, v0.z, v0.w, v1.x, v1.y, v1.z, v1.w};
                bf16x8 hi8, lo8;
                #pragma unroll
                for (int e = 0; e < 8; e++) {
                    unsigned short h = f2bf(vv[e]);
                    hi8[e] = (short)h;
                    lo8[e] = (short)f2bf(vv[e] - bf2f(h));
                }
                int ofs = row * 1024 + (k0 ^ ((row & 7) << 3));
                *(bf16x8*)&Hhi[ofs] = hi8;
                *(bf16x8*)&Hlo[ofs] = lo8;
            }
        } else {
            const u64* hsrc64 = (const u64*)(hcomm + (size_t)((t + 1) & 1) * BH_SZ);
            u64 pv[16];
            #pragma unroll
            for (int i = 0; i < 4; i++) {
                int c = i * 512 + tid;
                int row = c >> 7;
                int k0 = (c & 127) * 8;
                const u64* p = hsrc64 + (((size_t)(b0 + row) * HID + k0) >> 1);
                #pragma unroll
                for (int e = 0; e < 4; e++)
                    pv[i * 4 + e] = ld_coh_u64(p + e);
            }
            #pragma unroll
            for (int i = 0; i < 4; i++) {
                int c = i * 512 + tid;
                int row = c >> 7;
                int k0 = (c & 127) * 8;
                u32x4 hiu, lou;
                #pragma unroll
                for (int e = 0; e < 4; e++) {
                    u64 q = pv[i * 4 + e];
                    unsigned p0 = (unsigned)q;
                    unsigned p1 = (unsigned)(q >> 32);
                    hiu[e] = (p0 & 0xFFFFu) | (p1 << 16);
                    lou[e] = (p0 >> 16) | (p1 & 0xFFFF0000u);
                }
                int ofs = row * 1024 + (k0 ^ ((row & 7) << 3));
                *(u32x4*)&Hhi[ofs] = hiu;
                *(u32x4*)&Hlo[ofs] = lou;
            }
        }
        __syncthreads();   // sync A

        // ---- MFMA: W_hh·h (3-term, reg frags) + W_ih·x_t (1-term) ----
        {
            f32x4 acc0 = {0.f, 0.f, 0.f, 0.f};
            f32x4 acc1 = {0.f, 0.f, 0.f, 0.f};
            #pragma unroll
            for (int kk = 0; kk < 4; kk++) {
                int kidx = w * 128 + kk * 32 + ksub;
                int ofs  = frow * 1024 + (kidx ^ sw);
                bf16x8 ahi = *(const bf16x8*)&Hhi[ofs];
                bf16x8 alo = *(const bf16x8*)&Hlo[ofs];
                bf16x8 xh  = *(const bf16x8*)&Xh[ofs];
                bf16x8 wi  = *(const bf16x8*)&Wih[ofs];
                acc0 = __builtin_amdgcn_mfma_f32_16x16x32_bf16(ahi, wh[kk], acc0, 0, 0, 0);
                acc1 = __builtin_amdgcn_mfma_f32_16x16x32_bf16(ahi, wl[kk], acc1, 0, 0, 0);
                acc0 = __builtin_amdgcn_mfma_f32_16x16x32_bf16(alo, wh[kk], acc0, 0, 0, 0);
                acc1 = __builtin_amdgcn_mfma_f32_16x16x32_bf16(xh,  wi,     acc1, 0, 0, 0);
            }
            Pred[w][lane] = acc0 + acc1;
        }
        __syncthreads();   // sync B

        // ---- reduce + bias + tanh; coherent store (critical path) ----
        float hn = 0.f;
        if (tid < 256) {
            const int b = o >> 4, j = o & 15;
            const int plane = ((b >> 2) << 4) | j;
            const int pr = b & 3;
            float s = bias;
            #pragma unroll
            for (int k = 0; k < 8; k++) s += Pred[k][plane][pr];
            hn = fast_tanh(s);
            unsigned short hi = f2bf(hn);
            unsigned short lo = f2bf(hn - bf2f(hi));
            unsigned pk = (unsigned)hi | ((unsigned)lo << 16);
            st_coh_u32(hcomm + (size_t)(t & 1) * BH_SZ + out_off, pk);
        }
        __syncthreads();   // sync C: drains every thread's coherent h store

        // ---- arrive ----
        if (tid == 0) st_coh_u32(&flags[bid * 32], (unsigned)(t + 1));

        // ---- bubble work FIRST (v10/v13 ordering): out stores + x_{t+1} ----
        if (tid < 256) {
            out[(size_t)t * BH_SZ + out_off] = hn;
            if (t == T_STEPS - 1)
                out[(size_t)T_STEPS * BH_SZ + out_off] = hn;
        }
        if (t + 1 < T_STEPS) {
            if (xp16) {
                const unsigned short* xs = xp16 + (size_t)(t + 1) * BH_SZ;
                #pragma unroll
                for (int i = 0; i < 4; i++) {
                    int c = i * 512 + tid;
                    int row = c >> 7;
                    int k0 = (c & 127) * 8;
                    bf16x8 hi8 = *(const bf16x8*)(xs + (size_t)(b0 + row) * IN_DIM + k0);
                    int ofs = row * 1024 + (k0 ^ ((row & 7) << 3));
                    *(bf16x8*)&Xh[ofs] = hi8;   // reads done at prior sync B
                }
            } else {
                const float* xs = x + (size_t)(t + 1) * BH_SZ;   // B*I == BH_SZ
                #pragma unroll
                for (int i = 0; i < 4; i++) {
                    int c = i * 512 + tid;
                    int row = c >> 7;
                    int k0 = (c & 127) * 8;
                    const float* p = xs + (size_t)(b0 + row) * IN_DIM + k0;
                    float4 v0 = *(const float4*)(p);
                    float4 v1 = *(const float4*)(p + 4);
                    float vv[8] = {v0.x, v0.y, v0.z, v0.w, v1.x, v1.y, v1.z, v1.w};
                    bf16x8 hi8;
                    #pragma unroll
                    for (int e = 0; e < 8; e++) hi8[e] = (short)f2bf(vv[e]);
                    int ofs = row * 1024 + (k0 ^ ((row & 7) << 3));
                    *(bf16x8*)&Xh[ofs] = hi8;
                }
            }
        }

        // ---- wait: FULL grid, throttled poll (s_sleep(4) backoff) ----
        if (tid < 64) {
            const unsigned target = (unsigned)(t + 1);
            for (;;) {
                int ok = 1;
                #pragma unroll
                for (int g = 0; g < 4; g++) {
                    unsigned v = ld_coh_u32(&flags[(size_t)(tid + g * 64) * 32]);
                    ok &= (v >= target) ? 1 : 0;
                }
                if (__all(ok)) break;
                __builtin_amdgcn_s_sleep(4);
            }
        }
        __syncthreads();   // sync D
    }
}

// ---------------------------------------------------------------------------
extern "C" void kernel_launch(void* const* d_in, const int* in_sizes, int n_in,
                              void* d_out, int out_size, void* d_ws, size_t ws_size,
                              hipStream_t stream)
{
    const float* input  = (const float*)d_in[0];  // [T,B,I]
    const float* hidden = (const float*)d_in[1];  // [B,H]
    const float* W_ih   = (const float*)d_in[2];  // [H,I]
    const float* W_hh   = (const float*)d_in[3];  // [H,H]
    const float* b_ih   = (const float*)d_in[4];  // [H]
    const float* b_hh   = (const float*)d_in[5];  // [H]
    float* out = (float*)d_out;

    unsigned* flags = (unsigned*)d_ws;                          // 32 KB
    unsigned* hcomm = (unsigned*)((char*)d_ws + 256 * 32 * sizeof(unsigned));
    hipMemsetAsync(flags, 0, 256 * 32 * sizeof(unsigned), stream);

    // optional pre-packed x (bf16) at ws offset 1 MB, if workspace allows
    const size_t xpk_off  = (size_t)1 << 20;
    const size_t xpk_size = (size_t)T_STEPS * BH_SZ * sizeof(unsigned short);
    const unsigned short* xp16 = nullptr;
    if (ws_size >= xpk_off + xpk_size) {
        unsigned short* xp = (unsigned short*)((char*)d_ws + xpk_off);
        pack_x_kernel<<<2048, 256, 0, stream>>>(input, xp,
                                                (T_STEPS * BATCH * IN_DIM) / 8);
        xp16 = xp;
    }

    rnn_fused_kernel<<<256, 512, 0, stream>>>(
        input, xp16, hidden, W_ih, W_hh, b_ih, b_hh, out, hcomm, flags);
}